// Round 5
// baseline (220.028 us; speedup 1.0000x reference)
//
#include <hip/hip_runtime.h>

#define HW 262144
#define WID 512
#define PLANES 48
#define NCH 3
#define PAD 11
#define FW 23
#define TW 64    // tile out cols
#define TH 128   // tile out rows
#define XR 150   // xs rows (TH + 22)
#define XC 88    // xs row stride in shorts (86 data + 2 pad)
#define HC 64    // hs row stride in shorts

__device__ __forceinline__ unsigned pack_bf16(float a, float b) {
  unsigned ua = (__float_as_uint(a) + 0x8000u) >> 16;
  unsigned ub = (__float_as_uint(b) + 0x8000u) & 0xFFFF0000u;
  return ub | ua;
}
__device__ __forceinline__ float lo_bf16(unsigned u) { return __uint_as_float(u << 16); }
__device__ __forceinline__ float hi_bf16(unsigned u) { return __uint_as_float(u & 0xFFFF0000u); }
__device__ __forceinline__ void unpack8(uint4 v, float* f) {
  f[0] = lo_bf16(v.x); f[1] = hi_bf16(v.x);
  f[2] = lo_bf16(v.y); f[3] = hi_bf16(v.y);
  f[4] = lo_bf16(v.z); f[5] = hi_bf16(v.z);
  f[6] = lo_bf16(v.w); f[7] = hi_bf16(v.w);
}

// ---------- median: single-pass 8192-bin histogram over [-8,8) ----------
__global__ __launch_bounds__(256) void hist1_kernel(const float* __restrict__ x,
                                                    int* __restrict__ ghist1) {
  __shared__ int h[8192];
  const int p = blockIdx.x, s = blockIdx.y, tid = threadIdx.x;
  for (int i = tid; i < 8192; i += 256) h[i] = 0;
  __syncthreads();
  const float4* xv = (const float4*)(x + (size_t)p * HW + (size_t)s * (HW / 16));
#define H1(c) { int b = (int)(((c) + 8.0f) * 512.0f); b = min(max(b, 0), 8191); atomicAdd(&h[b], 1); }
  for (int i = tid; i < HW / 16 / 4; i += 256) {
    float4 v = xv[i];
    H1(v.x); H1(v.y); H1(v.z); H1(v.w);
  }
#undef H1
  __syncthreads();
  int* gh = ghist1 + p * 8192;
  const int st = (s * 512) & 8191;
  for (int k = tid; k < 8192; k += 256) {
    int i = (k + st) & 8191;
    int c = h[i];
    if (c) atomicAdd(&gh[i], c);
  }
}

// ---------- parallel median select (+ k1 prep piggybacked) ----------
__global__ __launch_bounds__(256) void scan_med_kernel(const int* __restrict__ ghist1,
                                                       float* __restrict__ med,
                                                       const float* __restrict__ kern,
                                                       float* __restrict__ k1g) {
  __shared__ int incl[256];
  __shared__ int s_chunk, s_base;
  const int p = blockIdx.x, t = threadIdx.x;
  if (p == 0 && t < FW) k1g[t] = kern[t * FW + PAD] / sqrtf(kern[PAD * FW + PAD]);
  const int* gh = ghist1 + p * 8192;
  int mysum = 0;
#pragma unroll
  for (int j = 0; j < 32; ++j) mysum += gh[t * 32 + j];
  incl[t] = mysum;
  __syncthreads();
  for (int off = 1; off < 256; off <<= 1) {
    int v = (t >= off) ? incl[t - off] : 0;
    __syncthreads();
    incl[t] += v;
    __syncthreads();
  }
  const int rank = 131072;
  {
    int excl = incl[t] - mysum;
    if (excl < rank && rank <= incl[t]) { s_chunk = t; s_base = rank - excl; }
  }
  __syncthreads();
  if (t < 64) {
    const int c = s_chunk, base = s_base;
    int cnt = (t < 32) ? gh[c * 32 + t] : 0;
    int pfx = cnt;
#pragma unroll
    for (int off = 1; off < 32; off <<= 1) {
      int u = __shfl_up(pfx, off, 64);
      if (t >= off) pfx += u;
    }
    unsigned long long m = __ballot(t < 32 && pfx >= base);
    int bin = c * 32 + (__ffsll((long long)m) - 1);
    if (t == 0) med[p] = -8.0f + ((float)bin + 0.5f) * 0.001953125f + 0.2f;
  }
}

// ---------- fused: separable 23x23 conv (bf16 LDS) + res-write + res-histogram ----------
__global__ __launch_bounds__(256) void conv_kernel(const float* __restrict__ x,
                                                   const float* __restrict__ mask,
                                                   const float* __restrict__ k1g,
                                                   const float* __restrict__ med,
                                                   float* __restrict__ res,
                                                   int* __restrict__ ghist) {
  __shared__ unsigned smem[11400];  // 45600 B: xs(26400) + hs(19200); reused as hist(32768)
  unsigned short* xs = (unsigned short*)smem;            // XR x XC shorts
  unsigned short* hs = (unsigned short*)smem + XR * XC;  // XR x HC shorts
  const int z = blockIdx.z;
  const int n = z / NCH;
  const int tbx = blockIdx.x, tby = blockIdx.y;
  const int tid = threadIdx.x;

  float k1[FW];
#pragma unroll
  for (int t = 0; t < FW; ++t) k1[t] = k1g[t];

  const float m_med = med[z];
  const int gr0 = tby * TH - PAD;
  const int gc0 = tbx * TW - PAD;
  const float* xb = x + (size_t)z * HW;
  const float* mb = mask + (size_t)n * HW;

  // staging: pairs of columns -> one packed bf16x2 write
  for (int i = tid; i < XR * (XC / 2); i += 256) {
    int r = i / (XC / 2), pc = i - r * (XC / 2);
    int gr = min(max(gr0 + r, 0), WID - 1);
    int gc = min(max(gc0 + 2 * pc, 0), WID - 1);
    int gc2 = min(max(gc0 + 2 * pc + 1, 0), WID - 1);
    float a = fmaf(mb[gr * WID + gc], xb[gr * WID + gc] - m_med, m_med);
    float b = fmaf(mb[gr * WID + gc2], xb[gr * WID + gc2] - m_med, m_med);
    ((unsigned*)xs)[r * (XC / 2) + pc] = pack_bf16(a, b);
  }
  __syncthreads();

  // horizontal: 8 outputs/task; XR rows x 8 groups
  for (int g = tid; g < XR * 8; g += 256) {
    int r = g >> 3, c0 = (g & 7) << 3;  // out col base
    const unsigned* row = (const unsigned*)&xs[r * XC] + (c0 >> 1);
    uint4 A = *(const uint4*)row;
    uint4 B = *(const uint4*)(row + 4);
    uint4 C = *(const uint4*)(row + 8);
    uint4 D = *(const uint4*)(row + 12);
    float w[32];
    unpack8(A, w); unpack8(B, w + 8); unpack8(C, w + 16); unpack8(D, w + 24);
    float a[8];
#pragma unroll
    for (int j = 0; j < 8; ++j) a[j] = 0.f;
#pragma unroll
    for (int t = 0; t < FW; ++t) {
      float k = k1[t];
#pragma unroll
      for (int j = 0; j < 8; ++j) a[j] = fmaf(k, w[t + j], a[j]);
    }
    uint4 o;
    o.x = pack_bf16(a[0], a[1]); o.y = pack_bf16(a[2], a[3]);
    o.z = pack_bf16(a[4], a[5]); o.w = pack_bf16(a[6], a[7]);
    *(uint4*)((unsigned*)&hs[r * HC] + (c0 >> 1)) = o;
  }
  __syncthreads();

  // vertical: 8 cols x 4 rows per thread
  const int ct = (tid & 7) << 3;   // out col base
  const int rt = (tid >> 3) << 2;  // out row base (0..124)
  float acc[4][8];
#pragma unroll
  for (int j = 0; j < 4; ++j)
#pragma unroll
    for (int q = 0; q < 8; ++q) acc[j][q] = 0.f;
#pragma unroll
  for (int tp = 0; tp <= 25; ++tp) {
    uint4 v = *(const uint4*)((const unsigned*)&hs[(rt + tp) * HC] + (ct >> 1));
    float f[8];
    unpack8(v, f);
    const int jlo = (tp - 22 > 0) ? (tp - 22) : 0;
    const int jhi = (tp < 3) ? tp : 3;
#pragma unroll
    for (int j = jlo; j <= jhi; ++j) {
      float k = k1[tp - j];
#pragma unroll
      for (int q = 0; q < 8; ++q) acc[j][q] = fmaf(k, f[q], acc[j][q]);
    }
  }

  // epilogue: res = 4*(xp - gauss); keep res in acc for histogram
  float* rb = res + (size_t)z * HW + (size_t)(tby * TH + rt) * WID + (tbx * TW + ct);
#pragma unroll
  for (int j = 0; j < 4; ++j) {
    const unsigned* xr = (const unsigned*)&xs[(rt + j + PAD) * XC] + ((ct + 8) >> 1);
    uint4 A = *(const uint4*)xr;        // shorts ct+8 .. ct+15
    uint4 B = *(const uint4*)(xr + 4);  // shorts ct+16 .. ct+23
    float xp[8];
    xp[0] = hi_bf16(A.y); xp[1] = lo_bf16(A.z); xp[2] = hi_bf16(A.z); xp[3] = lo_bf16(A.w);
    xp[4] = hi_bf16(A.w); xp[5] = lo_bf16(B.x); xp[6] = hi_bf16(B.x); xp[7] = lo_bf16(B.y);
    float4 o0, o1;
    o0.x = 4.0f * (xp[0] - acc[j][0]); o0.y = 4.0f * (xp[1] - acc[j][1]);
    o0.z = 4.0f * (xp[2] - acc[j][2]); o0.w = 4.0f * (xp[3] - acc[j][3]);
    o1.x = 4.0f * (xp[4] - acc[j][4]); o1.y = 4.0f * (xp[5] - acc[j][5]);
    o1.z = 4.0f * (xp[6] - acc[j][6]); o1.w = 4.0f * (xp[7] - acc[j][7]);
    *(float4*)&rb[(size_t)j * WID] = o0;
    *(float4*)&rb[(size_t)j * WID + 4] = o1;
    acc[j][0] = o0.x; acc[j][1] = o0.y; acc[j][2] = o0.z; acc[j][3] = o0.w;
    acc[j][4] = o1.x; acc[j][5] = o1.y; acc[j][6] = o1.z; acc[j][7] = o1.w;
  }

  // fused per-plane histogram of trunc(res*256), 8192 bins over [-16,16)
  __syncthreads();  // all xs/hs reads done
  int* hh = (int*)smem;
  for (int i = tid; i < 8192; i += 256) hh[i] = 0;
  __syncthreads();
#pragma unroll
  for (int j = 0; j < 4; ++j)
#pragma unroll
    for (int q = 0; q < 8; ++q) {
      int b = (int)(acc[j][q] * 256.0f) + 4096;
      b = min(max(b, 0), 8191);
      atomicAdd(&hh[b], 1);
    }
  __syncthreads();
  int* gh = ghist + z * 8192;
  const int st = ((tbx * 4 + tby) * 256) & 8191;
  for (int k = tid; k < 8192; k += 256) {
    int i = (k + st) & 8191;
    int c = hh[i];
    if (c) atomicAdd(&gh[i], c);
  }
}

// ---------- parallel percentile select ----------
__global__ __launch_bounds__(256) void pct_kernel(const int* __restrict__ ghist,
                                                  float* __restrict__ lo_out,
                                                  float* __restrict__ inv_out) {
  __shared__ int incl[256];
  __shared__ int s_chunk, s_base;
  __shared__ float s_v[4];
  const int p = blockIdx.x, t = threadIdx.x;
  const int* gh = ghist + p * 8192;
  int mysum = 0;
#pragma unroll
  for (int j = 0; j < 32; ++j) mysum += gh[t * 32 + j];
  incl[t] = mysum;
  __syncthreads();
  for (int off = 1; off < 256; off <<= 1) {
    int v = (t >= off) ? incl[t - off] : 0;
    __syncthreads();
    incl[t] += v;
    __syncthreads();
  }
  const int ranks[4] = {7865, 7866, 254279, 254280};
#pragma unroll
  for (int r = 0; r < 4; ++r) {
    const int rank = ranks[r];
    int excl = incl[t] - mysum;
    if (excl < rank && rank <= incl[t]) { s_chunk = t; s_base = rank - excl; }
    __syncthreads();
    if (t < 64) {
      const int c = s_chunk, base = s_base;
      int cnt = (t < 32) ? gh[c * 32 + t] : 0;
      int pfx = cnt;
#pragma unroll
      for (int off = 1; off < 32; off <<= 1) {
        int u = __shfl_up(pfx, off, 64);
        if (t >= off) pfx += u;
      }
      unsigned long long m = __ballot(t < 32 && pfx >= base);
      int bin = c * 32 + (__ffsll((long long)m) - 1);
      if (t == 0) s_v[r] = (float)(bin - 4096) * 0.00390625f;
    }
    __syncthreads();
  }
  if (t == 0) {
    const double fl = 0.29, fh = 0.71;
    double lov = (double)s_v[0] + fl * ((double)s_v[1] - (double)s_v[0]);
    double hiv = (double)s_v[2] + fh * ((double)s_v[3] - (double)s_v[2]);
    lo_out[p] = (float)lov;
    inv_out[p] = (float)(1.0 / (hiv - lov));
  }
}

// ---------- final normalize in place (res lives in d_out) ----------
__global__ __launch_bounds__(256) void final_kernel(float* __restrict__ res,
                                                    const float* __restrict__ mask,
                                                    const float* __restrict__ lo,
                                                    const float* __restrict__ inv) {
  const int i = blockIdx.x * 256 + threadIdx.x;
  const int e = i << 2;
  const int z = e >> 18;
  const int n = z / NCH;
  const int hw = e & (HW - 1);
  float4 r = ((const float4*)res)[i];
  float4 m = *(const float4*)(mask + (size_t)n * HW + hw);
  const float l = lo[z];
  const float iv = inv[z];
  float4 o;
  o.x = (r.x - l) * iv * m.x;
  o.y = (r.y - l) * iv * m.y;
  o.z = (r.z - l) * iv * m.z;
  o.w = (r.w - l) * iv * m.w;
  ((float4*)res)[i] = o;
}

extern "C" void kernel_launch(void* const* d_in, const int* in_sizes, int n_in,
                              void* d_out, int out_size, void* d_ws, size_t ws_size,
                              hipStream_t stream) {
  (void)in_sizes; (void)n_in; (void)out_size; (void)ws_size;
  const float* x = (const float*)d_in[0];
  const float* mask = (const float*)d_in[1];
  const float* kern = (const float*)d_in[2];
  float* out = (float*)d_out;  // doubles as res scratch

  int* ghist = (int*)d_ws;                // 48*8192 (res histogram)
  int* ghist1 = ghist + PLANES * 8192;    // 48*8192 (median histogram)
  float* med = (float*)(ghist1 + PLANES * 8192);
  float* lo = med + PLANES;
  float* inv = lo + PLANES;
  float* k1g = inv + PLANES;              // 23 floats

  hipMemsetAsync(ghist, 0, (size_t)PLANES * (8192 + 8192) * sizeof(int), stream);
  hist1_kernel<<<dim3(PLANES, 16), 256, 0, stream>>>(x, ghist1);
  scan_med_kernel<<<PLANES, 256, 0, stream>>>(ghist1, med, kern, k1g);
  conv_kernel<<<dim3(8, 4, PLANES), 256, 0, stream>>>(x, mask, k1g, med, out, ghist);
  pct_kernel<<<PLANES, 256, 0, stream>>>(ghist, lo, inv);
  final_kernel<<<(HW * PLANES / 4 + 255) / 256, 256, 0, stream>>>(out, mask, lo, inv);
}